// Round 3
// baseline (339.277 us; speedup 1.0000x reference)
//
#include <hip/hip_runtime.h>
#include <hip/hip_bf16.h>
#include <stdint.h>

// SoftTree: x(65536x512) f32, gw(512x255) f32, gb(255) f32, z(256x256) f32 -> out(65536x256) f32
// g = sigmoid(x@gw+gb); leaf = depth-8 tree products of g/(1-g); out = leaf @ z^T.

typedef short bf16x8 __attribute__((ext_vector_type(8)));
typedef float f32x4  __attribute__((ext_vector_type(4)));

__device__ __forceinline__ unsigned short f2bf(float f) {
    union { float f; uint32_t u; } c; c.f = f;
    uint32_t u = c.u;
    return (unsigned short)((u + 0x7FFFu + ((u >> 16) & 1u)) >> 16);
}
__device__ __forceinline__ float bf2f(unsigned short h) {
    union { uint32_t u; float f; } c; c.u = ((uint32_t)h) << 16; return c.f;
}
__device__ __forceinline__ uint32_t pkbf(float a, float b) {
    union { __hip_bfloat162 h; uint32_t u; } cv;
    cv.h = __float22bfloat162_rn(make_float2(a, b));   // v_cvt_pk_bf16_f32
    return cv.u;
}

// ---- prep: blocks 0..31 transpose gw (512x255 f32, gate-fast) -> gwt bf16 [gate][k] (256x512, row255=0)
//            blocks 32..95: z (256x256 f32) -> zb bf16
__global__ __launch_bounds__(256) void softtree_prep(
    const float* __restrict__ gw, const float* __restrict__ z,
    unsigned short* __restrict__ gwt, unsigned short* __restrict__ zb)
{
    if (blockIdx.x < 32) {
        __shared__ float tsm[64][65];
        const int k0 = (blockIdx.x >> 2) * 64;
        const int n0 = (blockIdx.x & 3) * 64;
        const int r = threadIdx.x >> 6;
        const int c = threadIdx.x & 63;
        const int n = n0 + c;
        #pragma unroll
        for (int i = 0; i < 16; ++i) {
            int kk = r + i * 4;
            tsm[kk][c] = (n < 255) ? gw[(size_t)(k0 + kk) * 255 + n] : 0.0f;
        }
        __syncthreads();
        #pragma unroll
        for (int i = 0; i < 16; ++i) {
            int nn = r + i * 4;
            gwt[(size_t)(n0 + nn) * 512 + k0 + c] = f2bf(tsm[c][nn]);
        }
    } else {
        int base = (blockIdx.x - 32) * 1024 + threadIdx.x * 4;
        const float4 v = *(const float4*)(z + base);
        ushort4 o;
        o.x = f2bf(v.x); o.y = f2bf(v.y); o.z = f2bf(v.z); o.w = f2bf(v.w);
        *(ushort4*)(zb + base) = o;
    }
}

// ---- main: 512 threads (8 waves), 64 rows/block, grid 1024 (exactly 4 blocks/CU resident).
// Wave = 16 rows (wr = wv&3) x 128 cols (wc = wv>>2).
// LDS 34048 B:
//   GEMM1 phase: bytes [0,32768) = gw chunk (256 gates x 64 k bf16), slot (gate,kg) at
//                (gate*8 + (kg ^ (gate&7)))*16  -- xor swizzle, conflict-free b128 frags
//   gates phase: unsigned short gs[64][266] (aliases; written only after GEMM1 done)
// x never touches LDS: each lane loads its own A-fragment (f32 -> cvt_pk_bf16 in regs).
__global__ __launch_bounds__(512, 4) void softtree_main(
    const float* __restrict__ x, const float* __restrict__ gb,
    const unsigned short* __restrict__ gwt, const unsigned short* __restrict__ zb,
    float* __restrict__ out)
{
    __shared__ char smraw[64 * 266 * 2];    // 34048 B >= 32768
    unsigned short* gs = (unsigned short*)smraw;

    const int tid  = threadIdx.x;
    const int lane = tid & 63;
    const int wv   = tid >> 6;
    const int q    = lane >> 4;
    const int l15  = lane & 15;
    const int wr   = wv & 3;
    const int wc   = wv >> 2;
    const int R0   = blockIdx.x * 64;
    const int row  = R0 + 16 * wr + l15;

    // ---- gw staging map: thread t handles (gate = t>>3 + 64j, kg = t&7), 16B each, j=0..3
    const int g0 = tid >> 3;
    const int kg = tid & 7;
    const unsigned short* gsrc0 = gwt + (size_t)g0 * 512 + kg * 8;
    char* gdst0 = smraw + (g0 * 8 + (kg ^ (g0 & 7))) * 16;

    // ---- per-lane x pointer (A-fragments direct from global)
    const float* xp = x + (size_t)row * 512 + q * 8;

    // ---- B-fragment LDS read bases (per s-subchunk)
    const char* bb0 = smraw + (128 * wc + l15) * 128 + (((4 * 0 + q) ^ (l15 & 7)) * 16);
    const char* bb1 = smraw + (128 * wc + l15) * 128 + (((4 * 1 + q) ^ (l15 & 7)) * 16);

    f32x4 acc[8];
    #pragma unroll
    for (int i = 0; i < 8; ++i) acc[i] = (f32x4){0.f, 0.f, 0.f, 0.f};

    // ---- prologue: chunk 0 gw -> regs, x chunk 0 -> regs
    uint4 gr4[4];
    #pragma unroll
    for (int j = 0; j < 4; ++j) gr4[j] = *(const uint4*)(gsrc0 + j * 32768);
    float4 xc0 = *(const float4*)(xp);
    float4 xc1 = *(const float4*)(xp + 4);
    float4 xc2 = *(const float4*)(xp + 32);
    float4 xc3 = *(const float4*)(xp + 36);

    // ---- GEMM1 K-loop: BK=64, 8 iters, reg-buffered gw staging, single LDS buffer
    for (int kc = 0; kc < 8; ++kc) {
        #pragma unroll
        for (int j = 0; j < 4; ++j) *(uint4*)(gdst0 + j * 8192) = gr4[j];
        __syncthreads();                       // chunk kc visible

        // cvt current x regs -> A-frags (frees xc for prefetch)
        bf16x8 afr[2];
        {
            union { bf16x8 v; uint32_t u[4]; } pk;
            pk.u[0] = pkbf(xc0.x, xc0.y); pk.u[1] = pkbf(xc0.z, xc0.w);
            pk.u[2] = pkbf(xc1.x, xc1.y); pk.u[3] = pkbf(xc1.z, xc1.w);
            afr[0] = pk.v;
            pk.u[0] = pkbf(xc2.x, xc2.y); pk.u[1] = pkbf(xc2.z, xc2.w);
            pk.u[2] = pkbf(xc3.x, xc3.y); pk.u[3] = pkbf(xc3.z, xc3.w);
            afr[1] = pk.v;
        }

        // prefetch chunk kc+1 (gw -> gr4, x -> xc); in flight through MFMA phase
        if (kc < 7) {
            const int ko = (kc + 1) * 64;
            #pragma unroll
            for (int j = 0; j < 4; ++j) gr4[j] = *(const uint4*)(gsrc0 + j * 32768 + ko);
            xc0 = *(const float4*)(xp + ko);
            xc1 = *(const float4*)(xp + ko + 4);
            xc2 = *(const float4*)(xp + ko + 32);
            xc3 = *(const float4*)(xp + ko + 36);
        }

        // MFMA on chunk kc: 2 s-subchunks x 8 n-tiles
        #pragma unroll
        for (int nt = 0; nt < 8; ++nt) {
            bf16x8 b0 = *(const bf16x8*)(bb0 + nt * 2048);
            acc[nt] = __builtin_amdgcn_mfma_f32_16x16x32_bf16(afr[0], b0, acc[nt], 0, 0, 0);
        }
        #pragma unroll
        for (int nt = 0; nt < 8; ++nt) {
            bf16x8 b1 = *(const bf16x8*)(bb1 + nt * 2048);
            acc[nt] = __builtin_amdgcn_mfma_f32_16x16x32_bf16(afr[1], b1, acc[nt], 0, 0, 0);
        }
        __syncthreads();                       // WAR: all reads done before next write
    }

    // ---- phase 2: sigmoid -> gs (bf16, stride 266: conflict-free tree reads)
    #pragma unroll
    for (int nt = 0; nt < 8; ++nt) {
        const int col = 128 * wc + nt * 16 + l15;
        const float gbv = (col < 255) ? gb[col] : 0.0f;
        #pragma unroll
        for (int r = 0; r < 4; ++r) {
            const int rowl = 16 * wr + 4 * q + r;
            float v = acc[nt][r] + gbv;
            gs[rowl * 266 + col] = f2bf(1.0f / (1.0f + __expf(-v)));
        }
    }
    __syncthreads();

    // ---- phase 3: tree -> GEMM2 A-frags. A[m=l15][k=c*32+q*8+j], leaf l = k, G = l>>3 = 4c+q
    const unsigned short* gr = gs + (16 * wr + l15) * 266;
    float t1v[2], t2v[4], t3v[8];
    {
        float g0v = bf2f(gr[0]);
        t1v[0] = g0v; t1v[1] = 1.0f - g0v;
        #pragma unroll
        for (int u = 0; u < 2; ++u) {
            float gl = bf2f(gr[1 + u]);
            t2v[2 * u] = t1v[u] * gl; t2v[2 * u + 1] = t1v[u] - t2v[2 * u];
        }
        #pragma unroll
        for (int u = 0; u < 4; ++u) {
            float gl = bf2f(gr[3 + u]);
            t3v[2 * u] = t2v[u] * gl; t3v[2 * u + 1] = t2v[u] - t3v[2 * u];
        }
    }
    bf16x8 a2[8];
    #pragma unroll
    for (int c = 0; c < 8; ++c) {
        const int G = c * 4 + q;
        float p = t3v[c];
        float g3 = bf2f(gr[7 + c]);
        p = (q & 2) ? (p - p * g3) : (p * g3);
        float g4 = bf2f(gr[15 + 2 * c + (q >> 1)]);
        p = (q & 1) ? (p - p * g4) : (p * g4);
        float g5 = bf2f(gr[31 + G]);
        float a0 = p * g5, a1 = p - a0;
        float g6a = bf2f(gr[63 + 2 * G]), g6b = bf2f(gr[64 + 2 * G]);
        float b00 = a0 * g6a, b01 = a0 - b00;
        float b10 = a1 * g6b, b11 = a1 - b10;
        float g70 = bf2f(gr[127 + 4 * G]), g71 = bf2f(gr[128 + 4 * G]);
        float g72 = bf2f(gr[129 + 4 * G]), g73 = bf2f(gr[130 + 4 * G]);
        float lf0 = b00 * g70, lf1 = b00 - lf0;
        float lf2 = b01 * g71, lf3 = b01 - lf2;
        float lf4 = b10 * g72, lf5 = b10 - lf4;
        float lf6 = b11 * g73, lf7 = b11 - lf6;
        union { bf16x8 v; uint32_t u[4]; } pk;
        pk.u[0] = pkbf(lf0, lf1);
        pk.u[1] = pkbf(lf2, lf3);
        pk.u[2] = pkbf(lf4, lf5);
        pk.u[3] = pkbf(lf6, lf7);
        a2[c] = pk.v;
    }

    // ---- GEMM2: out16x128 = leaf @ z^T, B-frags straight from L2-resident zb
    f32x4 acc2[8];
    #pragma unroll
    for (int i = 0; i < 8; ++i) acc2[i] = (f32x4){0.f, 0.f, 0.f, 0.f};
    #pragma unroll
    for (int nt = 0; nt < 8; ++nt) {
        const unsigned short* zrow = zb + (size_t)(128 * wc + nt * 16 + l15) * 256 + q * 8;
        #pragma unroll
        for (int c = 0; c < 8; ++c) {
            bf16x8 b = *(const bf16x8*)(zrow + c * 32);
            acc2[nt] = __builtin_amdgcn_mfma_f32_16x16x32_bf16(a2[c], b, acc2[nt], 0, 0, 0);
        }
    }

    // ---- epilogue
    #pragma unroll
    for (int nt = 0; nt < 8; ++nt) {
        const int col = 128 * wc + nt * 16 + l15;
        #pragma unroll
        for (int r = 0; r < 4; ++r) {
            const int orow = R0 + 16 * wr + 4 * q + r;
            out[(size_t)orow * 256 + col] = acc2[nt][r];
        }
    }
}

extern "C" void kernel_launch(void* const* d_in, const int* in_sizes, int n_in,
                              void* d_out, int out_size, void* d_ws, size_t ws_size,
                              hipStream_t stream) {
    const float* x  = (const float*)d_in[0];
    const float* gw = (const float*)d_in[1];
    const float* gb = (const float*)d_in[2];
    const float* z  = (const float*)d_in[3];
    float* outp = (float*)d_out;

    unsigned short* gwt = (unsigned short*)d_ws;     // 256*512 bf16 = 256 KB
    unsigned short* zbf = gwt + 256 * 512;           // 256*256 bf16 = 128 KB

    softtree_prep<<<96, 256, 0, stream>>>(gw, z, gwt, zbf);
    softtree_main<<<1024, 512, 0, stream>>>(x, gb, gwt, zbf, outp);
}